// Round 2
// baseline (199.981 us; speedup 1.0000x reference)
//
#include <hip/hip_runtime.h>
#include <math.h>

// Constants folded exactly as JAX weak-typing does: python double -> f32.
#define DT_F        ((float)0.01)
#define HALF_DT_F   ((float)(0.5 * 0.01))
#define DT6_F       ((float)(0.01 / 6.0))
#define K_DRAG_F    ((float)0.05)
#define INV_2PI_F   0.15915494309189535f   // inline constant on gfx9

// Hardware trig: v_sin_f32 / v_cos_f32 take revolutions. |angle| here is
// O(10) rad -> |rev| < 2, well inside the valid hw input domain.
__device__ __forceinline__ void hw_sincos(float a, float* s, float* c) {
    const float r = a * INV_2PI_F;
    *s = __builtin_amdgcn_sinf(r);
    *c = __builtin_amdgcn_cosf(r);
}

__device__ __forceinline__ void dyn(const float* __restrict__ s,
                                    float u0, float tx, float ty, float tz,
                                    float iI0, float iI1, float iI2,
                                    float I0, float I1, float I2,
                                    float gx, float gy, float gz,
                                    float* __restrict__ k)
{
    const float vx = s[3], vy = s[4], vz = s[5];
    const float roll = s[6], pitch = s[7], yaw = s[8];
    const float wx = s[9], wy = s[10], wz = s[11];

    // roll / yaw: hardware trig (error ~1e-6, enters only bounded or
    // relative-error paths). pitch: precise — its cos feeds 1/c_pitch where
    // absolute error is amplified by up to 1e12 near the singularity.
    float s_r, c_r, s_p, c_p, s_y, c_y;
    hw_sincos(roll, &s_r, &c_r);
    sincosf(pitch, &s_p, &c_p);
    hw_sincos(yaw,  &s_y, &c_y);

    // Third column of R (body z-axis in world frame)
    const float spcr = s_p * c_r;
    const float r02 = c_y * spcr + s_y * s_r;
    const float r12 = s_y * spcr - c_y * s_r;
    const float r22 = c_p * c_r;

    float vn = __builtin_amdgcn_sqrtf(vx * vx + vy * vy + vz * vz);
    vn = fmaxf(vn, 1e-8f);
    const float dscale = -K_DRAG_F * vn;

    // M == 1.0 -> skip the divide
    const float ax = r02 * u0 + dscale * vx + gx;
    const float ay = r12 * u0 + dscale * vy + gy;
    const float az = r22 * u0 + dscale * vz + gz;

    // omega_cross = omega x (omega * I); omega_dot = (tau - cross) / I
    const float bx = wx * I0, by = wy * I1, bz = wz * I2;
    const float cx = wy * bz - wz * by;
    const float cy = wz * bx - wx * bz;
    const float cz = wx * by - wy * bx;
    const float wdx = (tx - cx) * iI0;
    const float wdy = (ty - cy) * iI1;
    const float wdz = (tz - cz) * iI2;

    // Euler-angle kinematics with clamped cos(pitch); one rcp reused 3x —
    // rcp's ~1ulp relative error stays relative through the singular path.
    const float c_pitch = (fabsf(c_p) < 1e-6f) ? 1e-6f : c_p;
    const float inv_cp = __builtin_amdgcn_rcpf(c_pitch);
    const float t_pitch = s_p * inv_cp;
    const float roll_dot  = wx + s_r * t_pitch * wy + c_r * t_pitch * wz;
    const float pitch_dot = c_r * wy - s_r * wz;
    const float yaw_dot   = (s_r * inv_cp) * wy + (c_r * inv_cp) * wz;

    k[0] = vx;  k[1] = vy;  k[2] = vz;
    k[3] = ax;  k[4] = ay;  k[5] = az;
    k[6] = roll_dot; k[7] = pitch_dot; k[8] = yaw_dot;
    k[9] = wdx; k[10] = wdy; k[11] = wdz;
}

__global__ __launch_bounds__(256)
void drone_rk4_kernel(const float* __restrict__ state,
                      const float* __restrict__ u,
                      const float* __restrict__ I,
                      const float* __restrict__ g,
                      float* __restrict__ out, int B)
{
    const int i = blockIdx.x * blockDim.x + threadIdx.x;
    if (i >= B) return;

    const float4* sp = reinterpret_cast<const float4*>(state) + (size_t)i * 3;
    const float4 a0 = sp[0];
    const float4 a1 = sp[1];
    const float4 a2 = sp[2];
    float s0[12] = {a0.x, a0.y, a0.z, a0.w,
                    a1.x, a1.y, a1.z, a1.w,
                    a2.x, a2.y, a2.z, a2.w};
    const float4 uu = reinterpret_cast<const float4*>(u)[i];

    const float I0 = I[0], I1 = I[1], I2 = I[2];
    const float gx = g[0], gy = g[1], gz = g[2];
    // Hoisted reciprocals: 3 rcp/thread instead of 12 divides.
    const float iI0 = __builtin_amdgcn_rcpf(I0);
    const float iI1 = __builtin_amdgcn_rcpf(I1);
    const float iI2 = __builtin_amdgcn_rcpf(I2);

    float k1[12], k2[12], k3[12], k4[12], tmp[12];

    dyn(s0, uu.x, uu.y, uu.z, uu.w, iI0, iI1, iI2, I0, I1, I2, gx, gy, gz, k1);
    #pragma unroll
    for (int j = 0; j < 12; ++j) tmp[j] = fmaf(HALF_DT_F, k1[j], s0[j]);
    dyn(tmp, uu.x, uu.y, uu.z, uu.w, iI0, iI1, iI2, I0, I1, I2, gx, gy, gz, k2);
    #pragma unroll
    for (int j = 0; j < 12; ++j) tmp[j] = fmaf(HALF_DT_F, k2[j], s0[j]);
    dyn(tmp, uu.x, uu.y, uu.z, uu.w, iI0, iI1, iI2, I0, I1, I2, gx, gy, gz, k3);
    #pragma unroll
    for (int j = 0; j < 12; ++j) tmp[j] = fmaf(DT_F, k3[j], s0[j]);
    dyn(tmp, uu.x, uu.y, uu.z, uu.w, iI0, iI1, iI2, I0, I1, I2, gx, gy, gz, k4);

    float o[12];
    #pragma unroll
    for (int j = 0; j < 12; ++j)
        o[j] = s0[j] + DT6_F * (k1[j] + 2.0f * k2[j] + 2.0f * k3[j] + k4[j]);

    float4* op = reinterpret_cast<float4*>(out) + (size_t)i * 3;
    op[0] = make_float4(o[0], o[1], o[2], o[3]);
    op[1] = make_float4(o[4], o[5], o[6], o[7]);
    op[2] = make_float4(o[8], o[9], o[10], o[11]);
}

extern "C" void kernel_launch(void* const* d_in, const int* in_sizes, int n_in,
                              void* d_out, int out_size, void* d_ws, size_t ws_size,
                              hipStream_t stream)
{
    const float* state = (const float*)d_in[0];
    const float* u     = (const float*)d_in[1];
    const float* I     = (const float*)d_in[2];
    const float* g     = (const float*)d_in[3];
    float* out = (float*)d_out;

    const int B = in_sizes[0] / 12;
    const int block = 256;
    const int grid = (B + block - 1) / block;
    drone_rk4_kernel<<<grid, block, 0, stream>>>(state, u, I, g, out, B);
}

// Round 3
// 196.972 us; speedup vs baseline: 1.0153x; 1.0153x over previous
//
#include <hip/hip_runtime.h>
#include <math.h>

// Constants folded exactly as JAX weak-typing does: python double -> f32.
#define DT_F        ((float)0.01)
#define HALF_DT_F   ((float)(0.5 * 0.01))
#define DT6_F       ((float)(0.01 / 6.0))
#define K_DRAG_F    ((float)0.05)
#define INV_2PI_F   0.15915494309189535f
#define BLOCK 256

// Hardware trig: v_sin_f32 / v_cos_f32 take revolutions. |angle| here is
// O(10) rad -> |rev| < 2, inside the valid hw input domain.
__device__ __forceinline__ void hw_sincos(float a, float* s, float* c) {
    const float r = a * INV_2PI_F;
    *s = __builtin_amdgcn_sinf(r);
    *c = __builtin_amdgcn_cosf(r);
}

__device__ __forceinline__ void dyn(const float* __restrict__ s,
                                    float u0, float tx, float ty, float tz,
                                    float iI0, float iI1, float iI2,
                                    float I0, float I1, float I2,
                                    float gx, float gy, float gz,
                                    float* __restrict__ k)
{
    const float vx = s[3], vy = s[4], vz = s[5];
    const float roll = s[6], pitch = s[7], yaw = s[8];
    const float wx = s[9], wy = s[10], wz = s[11];

    // roll/yaw: hw trig (abs err ~1e-6, enters bounded/relative paths only).
    // pitch: precise ocml — its cos feeds 1/c_pitch (abs err amplified ~1e12
    // at the clamp); absmax=1.0 last round shows the singular path is live.
    float s_r, c_r, s_p, c_p, s_y, c_y;
    hw_sincos(roll, &s_r, &c_r);
    sincosf(pitch, &s_p, &c_p);
    hw_sincos(yaw,  &s_y, &c_y);

    const float spcr = s_p * c_r;
    const float r02 = c_y * spcr + s_y * s_r;
    const float r12 = s_y * spcr - c_y * s_r;
    const float r22 = c_p * c_r;

    float vn = __builtin_amdgcn_sqrtf(vx * vx + vy * vy + vz * vz);
    vn = fmaxf(vn, 1e-8f);
    const float dscale = -K_DRAG_F * vn;

    const float ax = r02 * u0 + dscale * vx + gx;   // M == 1.0
    const float ay = r12 * u0 + dscale * vy + gy;
    const float az = r22 * u0 + dscale * vz + gz;

    const float bx = wx * I0, by = wy * I1, bz = wz * I2;
    const float cx = wy * bz - wz * by;
    const float cy = wz * bx - wx * bz;
    const float cz = wx * by - wy * bx;
    const float wdx = (tx - cx) * iI0;
    const float wdy = (ty - cy) * iI1;
    const float wdz = (tz - cz) * iI2;

    const float c_pitch = (fabsf(c_p) < 1e-6f) ? 1e-6f : c_p;
    const float inv_cp = __builtin_amdgcn_rcpf(c_pitch);
    const float t_pitch = s_p * inv_cp;
    const float roll_dot  = wx + s_r * t_pitch * wy + c_r * t_pitch * wz;
    const float pitch_dot = c_r * wy - s_r * wz;
    const float yaw_dot   = (s_r * inv_cp) * wy + (c_r * inv_cp) * wz;

    k[0] = vx;  k[1] = vy;  k[2] = vz;
    k[3] = ax;  k[4] = ay;  k[5] = az;
    k[6] = roll_dot; k[7] = pitch_dot; k[8] = yaw_dot;
    k[9] = wdx; k[10] = wdy; k[11] = wdz;
}

__global__ __launch_bounds__(BLOCK)
void drone_rk4_kernel(const float* __restrict__ state,
                      const float* __restrict__ u,
                      const float* __restrict__ I,
                      const float* __restrict__ g,
                      float* __restrict__ out, int B)
{
    // 12 KB staging buffer: block's state region in, results out.
    __shared__ float4 lds[BLOCK * 3];

    const int t = threadIdx.x;
    const long long base = (long long)blockIdx.x * BLOCK;  // first drone of block
    const long long nvec = (long long)B * 3;               // total float4s
    const bool valid = (base + t) < B;

    // --- stage-in: 3 rounds of dense, fully-coalesced float4 loads ---
    const float4* sv = reinterpret_cast<const float4*>(state);
    #pragma unroll
    for (int r = 0; r < 3; ++r) {
        const long long f = base * 3 + r * BLOCK + t;
        if (f < nvec) lds[r * BLOCK + t] = sv[f];
    }
    __syncthreads();

    // Own row: LDS float4 index 3t (48 B lane stride). For ds_read_b128,
    // 8 consecutive lanes cover all 32 banks exactly once -> conflict-free.
    const float4 a0 = lds[t * 3 + 0];
    const float4 a1 = lds[t * 3 + 1];
    const float4 a2 = lds[t * 3 + 2];
    __syncthreads();   // all reads done before the buffer is reused for output

    float s0[12] = {a0.x, a0.y, a0.z, a0.w,
                    a1.x, a1.y, a1.z, a1.w,
                    a2.x, a2.y, a2.z, a2.w};

    // u rows are dense 16 B/lane already — direct load, guarded for tail.
    float4 uu = make_float4(0.f, 0.f, 0.f, 0.f);
    if (valid) uu = reinterpret_cast<const float4*>(u)[base + t];

    const float I0 = I[0], I1 = I[1], I2 = I[2];
    const float gx = g[0], gy = g[1], gz = g[2];
    const float iI0 = __builtin_amdgcn_rcpf(I0);
    const float iI1 = __builtin_amdgcn_rcpf(I1);
    const float iI2 = __builtin_amdgcn_rcpf(I2);

    float k1[12], k2[12], k3[12], k4[12], tmp[12];

    dyn(s0, uu.x, uu.y, uu.z, uu.w, iI0, iI1, iI2, I0, I1, I2, gx, gy, gz, k1);
    #pragma unroll
    for (int j = 0; j < 12; ++j) tmp[j] = fmaf(HALF_DT_F, k1[j], s0[j]);
    dyn(tmp, uu.x, uu.y, uu.z, uu.w, iI0, iI1, iI2, I0, I1, I2, gx, gy, gz, k2);
    #pragma unroll
    for (int j = 0; j < 12; ++j) tmp[j] = fmaf(HALF_DT_F, k2[j], s0[j]);
    dyn(tmp, uu.x, uu.y, uu.z, uu.w, iI0, iI1, iI2, I0, I1, I2, gx, gy, gz, k3);
    #pragma unroll
    for (int j = 0; j < 12; ++j) tmp[j] = fmaf(DT_F, k3[j], s0[j]);
    dyn(tmp, uu.x, uu.y, uu.z, uu.w, iI0, iI1, iI2, I0, I1, I2, gx, gy, gz, k4);

    float o[12];
    #pragma unroll
    for (int j = 0; j < 12; ++j)
        o[j] = s0[j] + DT6_F * (k1[j] + 2.0f * k2[j] + 2.0f * k3[j] + k4[j]);

    // --- stage-out through the same LDS buffer ---
    lds[t * 3 + 0] = make_float4(o[0], o[1], o[2],  o[3]);
    lds[t * 3 + 1] = make_float4(o[4], o[5], o[6],  o[7]);
    lds[t * 3 + 2] = make_float4(o[8], o[9], o[10], o[11]);
    __syncthreads();

    float4* ov = reinterpret_cast<float4*>(out);
    #pragma unroll
    for (int r = 0; r < 3; ++r) {
        const long long f = base * 3 + r * BLOCK + t;
        if (f < nvec) ov[f] = lds[r * BLOCK + t];
    }
}

extern "C" void kernel_launch(void* const* d_in, const int* in_sizes, int n_in,
                              void* d_out, int out_size, void* d_ws, size_t ws_size,
                              hipStream_t stream)
{
    const float* state = (const float*)d_in[0];
    const float* u     = (const float*)d_in[1];
    const float* I     = (const float*)d_in[2];
    const float* g     = (const float*)d_in[3];
    float* out = (float*)d_out;

    const int B = in_sizes[0] / 12;
    const int grid = (B + BLOCK - 1) / BLOCK;
    drone_rk4_kernel<<<grid, BLOCK, 0, stream>>>(state, u, I, g, out, B);
}